// Round 1
// baseline (460.477 us; speedup 1.0000x reference)
//
#include <hip/hip_runtime.h>
#include <cstdint>
#include <cstddef>

// ---------- types ----------
typedef __attribute__((ext_vector_type(8))) __bf16 bf16x8;
typedef __attribute__((ext_vector_type(4))) __bf16 bf16x4;
typedef __attribute__((ext_vector_type(4))) float  f32x4;

// split f32 into hi/lo bf16 (x ~= hi + lo, ~16-bit mantissa coverage)
__device__ __forceinline__ void split4(const float4 v, bf16x4& h, bf16x4& l) {
    __bf16 h0 = (__bf16)v.x; float r0 = v.x - (float)h0;
    __bf16 h1 = (__bf16)v.y; float r1 = v.y - (float)h1;
    __bf16 h2 = (__bf16)v.z; float r2 = v.z - (float)h2;
    __bf16 h3 = (__bf16)v.w; float r3 = v.w - (float)h3;
    h[0] = h0; h[1] = h1; h[2] = h2; h[3] = h3;
    l[0] = (__bf16)r0; l[1] = (__bf16)r1; l[2] = (__bf16)r2; l[3] = (__bf16)r3;
}

// ---------- GEMM (bt form): C[m,n] = sum_k A[m,k] * B[n,k]  (+ bias[n]) ----------
// 128x128 tile, BK=32, 256 threads (4 waves of 64x64), bf16x2 split MFMA.
// Batch via blockIdx.z with element strides.
__global__ __launch_bounds__(256)
void gemm_bt_split(const float* __restrict__ A, int lda, size_t strideA,
                   const float* __restrict__ B, int ldb, size_t strideB,
                   float* __restrict__ C, int ldc, size_t strideC,
                   int K, const float* __restrict__ bias)
{
    constexpr int BM = 128, BN = 128, BK = 32;
    constexpr int LDT = 48;  // LDS row stride in elems (96B: 16B-aligned, conflict-mild)
    __shared__ __attribute__((aligned(16))) __bf16 Ah[BM * LDT];
    __shared__ __attribute__((aligned(16))) __bf16 Al[BM * LDT];
    __shared__ __attribute__((aligned(16))) __bf16 Bh[BN * LDT];
    __shared__ __attribute__((aligned(16))) __bf16 Bl[BN * LDT];

    const int tid = threadIdx.x;
    const int m0 = blockIdx.y * BM;
    const int n0 = blockIdx.x * BN;
    const float* Ab = A + strideA * blockIdx.z + (size_t)m0 * lda;
    const float* Bb = B + strideB * blockIdx.z + (size_t)n0 * ldb;

    const int lane = tid & 63;
    const int wid  = tid >> 6;          // 0..3
    const int wm   = (wid >> 1) * 64;   // wave row offset in tile
    const int wn   = (wid & 1)  * 64;   // wave col offset in tile
    const int fr   = lane & 15;         // fragment row/col within 16
    const int koff = (lane >> 4) << 3;  // k offset within 32 (0,8,16,24)

    f32x4 acc[4][4] = {};

    for (int k0 = 0; k0 < K; k0 += BK) {
        __syncthreads();  // protect previous iteration's fragment reads
        // stage A and B tiles: 128x32 f32 each -> split to hi/lo bf16 in LDS
        #pragma unroll
        for (int i = 0; i < 4; ++i) {
            int f4  = tid + 256 * i;       // 0..1023 float4 slots
            int row = f4 >> 3;             // 8 float4 per row
            int c4  = (f4 & 7) << 2;       // col in elems
            float4 va = *(const float4*)(Ab + (size_t)row * lda + (k0 + c4));
            bf16x4 h, l;
            split4(va, h, l);
            *(bf16x4*)&Ah[row * LDT + c4] = h;
            *(bf16x4*)&Al[row * LDT + c4] = l;
            float4 vb = *(const float4*)(Bb + (size_t)row * ldb + (k0 + c4));
            split4(vb, h, l);
            *(bf16x4*)&Bh[row * LDT + c4] = h;
            *(bf16x4*)&Bl[row * LDT + c4] = l;
        }
        __syncthreads();

        bf16x8 ah[4], al[4], bh[4], bl[4];
        #pragma unroll
        for (int mi = 0; mi < 4; ++mi) {
            int r = wm + mi * 16 + fr;
            ah[mi] = *(const bf16x8*)&Ah[r * LDT + koff];
            al[mi] = *(const bf16x8*)&Al[r * LDT + koff];
        }
        #pragma unroll
        for (int ni = 0; ni < 4; ++ni) {
            int r = wn + ni * 16 + fr;
            bh[ni] = *(const bf16x8*)&Bh[r * LDT + koff];
            bl[ni] = *(const bf16x8*)&Bl[r * LDT + koff];
        }
        #pragma unroll
        for (int mi = 0; mi < 4; ++mi) {
            #pragma unroll
            for (int ni = 0; ni < 4; ++ni) {
                acc[mi][ni] = __builtin_amdgcn_mfma_f32_16x16x32_bf16(ah[mi], bh[ni], acc[mi][ni], 0, 0, 0);
                acc[mi][ni] = __builtin_amdgcn_mfma_f32_16x16x32_bf16(al[mi], bh[ni], acc[mi][ni], 0, 0, 0);
                acc[mi][ni] = __builtin_amdgcn_mfma_f32_16x16x32_bf16(ah[mi], bl[ni], acc[mi][ni], 0, 0, 0);
            }
        }
    }

    // epilogue: C/D layout col=lane&15, row=(lane>>4)*4+reg  [m89-verified]
    float* Cb = C + strideC * blockIdx.z;
    const int rbase = (lane >> 4) * 4;
    const int ccol  = lane & 15;
    #pragma unroll
    for (int ni = 0; ni < 4; ++ni) {
        int col = n0 + wn + ni * 16 + ccol;
        float bv = bias ? bias[col] : 0.0f;
        #pragma unroll
        for (int mi = 0; mi < 4; ++mi) {
            #pragma unroll
            for (int r = 0; r < 4; ++r) {
                int rowg = m0 + wm + mi * 16 + rbase + r;
                Cb[(size_t)rowg * ldc + col] = acc[mi][ni][r] + bv;
            }
        }
    }
}

// ---------- causal softmax, faithful to the buggy reference ----------
// in-place on scores[b, row, :]: real(t<=row): x*(1/32)+1e-13 ; masked(t>row): -1e-13
// softmax over ALL S entries (masked ones contribute exp(-m)/Z).
__global__ __launch_bounds__(256)
void softmax_causal(float* __restrict__ P, int S)
{
    const int row = blockIdx.x;
    float* p = P + ((size_t)blockIdx.y * S + row) * (size_t)S;
    const int tid = threadIdx.x;
    const int lane = tid & 63;
    const int wid  = tid >> 6;

    float v[8];
    float4 x0 = *(const float4*)(p + tid * 4);
    float4 x1 = *(const float4*)(p + 1024 + tid * 4);
    const float xs[8] = {x0.x, x0.y, x0.z, x0.w, x1.x, x1.y, x1.z, x1.w};
    #pragma unroll
    for (int j = 0; j < 8; ++j) {
        int col = (j < 4) ? (tid * 4 + j) : (1024 + tid * 4 + (j - 4));
        v[j] = (col > row) ? -1e-13f : fmaf(xs[j], 0.03125f, 1e-13f);
    }

    float m = v[0];
    #pragma unroll
    for (int j = 1; j < 8; ++j) m = fmaxf(m, v[j]);
    #pragma unroll
    for (int off = 1; off < 64; off <<= 1) m = fmaxf(m, __shfl_xor(m, off));
    __shared__ float red[8];
    if (lane == 0) red[wid] = m;
    __syncthreads();
    m = fmaxf(fmaxf(red[0], red[1]), fmaxf(red[2], red[3]));

    float s = 0.0f;
    #pragma unroll
    for (int j = 0; j < 8; ++j) { v[j] = expf(v[j] - m); s += v[j]; }
    #pragma unroll
    for (int off = 1; off < 64; off <<= 1) s += __shfl_xor(s, off);
    if (lane == 0) red[4 + wid] = s;
    __syncthreads();
    s = red[4] + red[5] + red[6] + red[7];
    const float inv = 1.0f / s;

    float4 o0, o1;
    o0.x = v[0] * inv; o0.y = v[1] * inv; o0.z = v[2] * inv; o0.w = v[3] * inv;
    o1.x = v[4] * inv; o1.y = v[5] * inv; o1.z = v[6] * inv; o1.w = v[7] * inv;
    *(float4*)(p + tid * 4) = o0;
    *(float4*)(p + 1024 + tid * 4) = o1;
}

// ---------- launch ----------
extern "C" void kernel_launch(void* const* d_in, const int* in_sizes, int n_in,
                              void* d_out, int out_size, void* d_ws, size_t ws_size,
                              hipStream_t stream)
{
    const float* Q  = (const float*)d_in[0];   // [B,S,D]
    const float* Km = (const float*)d_in[1];   // [B,S,D]
    const float* V  = (const float*)d_in[2];   // [B,D,S]
    const float* W  = (const float*)d_in[3];   // [E,D]
    const float* bv = (const float*)d_in[4];   // [E]
    float* out = (float*)d_out;                // [B,S,E]

    constexpr int B = 4, S = 2048, D = 1024, E = 1024;
    const dim3 blk(256);

    const size_t needBatched = ((size_t)B * S * S + (size_t)B * S * D) * sizeof(float);
    if (ws_size >= needBatched) {
        float* scores = (float*)d_ws;                    // [B,S,S]
        float* attn   = scores + (size_t)B * S * S;      // [B,S,D]
        // 1) scores = Q . K^T (raw dots; scale+eps applied in softmax)
        gemm_bt_split<<<dim3(S / 128, S / 128, B), blk, 0, stream>>>(
            Q, D, (size_t)S * D, Km, D, (size_t)S * D,
            scores, S, (size_t)S * S, D, nullptr);
        // 2) softmax in place -> P
        softmax_causal<<<dim3(S, B), blk, 0, stream>>>(scores, S);
        // 3) attn_out = P . V^T  (V stored [D,S] => bt form)
        gemm_bt_split<<<dim3(D / 128, S / 128, B), blk, 0, stream>>>(
            scores, S, (size_t)S * S, V, S, (size_t)D * S,
            attn, D, (size_t)S * D, S, nullptr);
        // 4) out = attn_out . W^T + b   (flat M = B*S)
        gemm_bt_split<<<dim3(E / 128, (B * S) / 128, 1), blk, 0, stream>>>(
            attn, D, 0, W, D, 0, out, E, 0, D, bv);
    } else {
        // per-batch fallback (24 MB workspace)
        float* sc   = (float*)d_ws;                 // [S,S]
        float* attn = sc + (size_t)S * S;           // [S,D]
        for (int b = 0; b < B; ++b) {
            const float* Qb = Q  + (size_t)b * S * D;
            const float* Kb = Km + (size_t)b * S * D;
            const float* Vb = V  + (size_t)b * D * S;
            float* outb = out + (size_t)b * S * E;
            gemm_bt_split<<<dim3(S / 128, S / 128, 1), blk, 0, stream>>>(
                Qb, D, 0, Kb, D, 0, sc, S, 0, D, nullptr);
            softmax_causal<<<dim3(S, 1), blk, 0, stream>>>(sc, S);
            gemm_bt_split<<<dim3(D / 128, S / 128, 1), blk, 0, stream>>>(
                sc, S, 0, Vb, S, 0, attn, D, 0, S, nullptr);
            gemm_bt_split<<<dim3(E / 128, S / 128, 1), blk, 0, stream>>>(
                attn, D, 0, W, D, 0, outb, E, 0, D, bv);
        }
    }
}

// Round 4
// 414.245 us; speedup vs baseline: 1.1116x; 1.1116x over previous
//
#include <hip/hip_runtime.h>
#include <cstdint>
#include <cstddef>

// ---------- types ----------
typedef _Float16 f16;
typedef __attribute__((ext_vector_type(8))) _Float16 f16x8;
typedef __attribute__((ext_vector_type(4))) _Float16 f16x4;
typedef __attribute__((ext_vector_type(4))) float    f32x4;
typedef __attribute__((ext_vector_type(8))) __bf16   bf16x8;
typedef __attribute__((ext_vector_type(4))) __bf16   bf16x4;

typedef __attribute__((address_space(1))) const uint32_t gu32;
typedef __attribute__((address_space(3))) uint32_t       lu32;

__device__ __forceinline__ void gload16(const void* g, void* l) {
    // async global->LDS, 16B per lane; LDS dest is wave-uniform base + lane*16
    __builtin_amdgcn_global_load_lds((gu32*)g, (lu32*)l, 16, 0, 0);
}

// ---------- conversion: f32 -> fp16 hi/lo planes ----------
__global__ __launch_bounds__(256)
void split_f32_to_f16(const float* __restrict__ in, f16* __restrict__ h,
                      f16* __restrict__ l, int n4)
{
    int i = blockIdx.x * blockDim.x + threadIdx.x;
    const int stride = gridDim.x * blockDim.x;
    for (; i < n4; i += stride) {
        float4 x = ((const float4*)in)[i];
        f16x4 hv, lv;
        hv[0] = (f16)x.x; lv[0] = (f16)(x.x - (float)hv[0]);
        hv[1] = (f16)x.y; lv[1] = (f16)(x.y - (float)hv[1]);
        hv[2] = (f16)x.z; lv[2] = (f16)(x.z - (float)hv[2]);
        hv[3] = (f16)x.w; lv[3] = (f16)(x.w - (float)hv[3]);
        ((f16x4*)h)[i] = hv;
        ((f16x4*)l)[i] = lv;
    }
}

// ---------- fp16 split GEMM (bt form): C[m,n] = sum_k A[m,k]*B[n,k] ----------
// 128x128 tile, BK=32, 256 threads (4 waves, 64x64 each), global_load_lds staging.
// NA/NB: split planes per operand (1 or 2). Terms: Ah*Bh [+ Al*Bh] [+ Ah*Bl].
// OUTK: 0 = f32 (+bias), 1 = fp16, 2 = fp16 hi/lo pair (Cv=hi, Cl2=lo).
// CAUSAL: triangular grid over blockIdx.x.
template<int NA, int NB, int OUTK, bool CAUSAL>
__global__ __launch_bounds__(256)
void gemm_f16(const f16* __restrict__ Ah, const f16* __restrict__ Al, int lda, size_t sA,
              const f16* __restrict__ Bh, const f16* __restrict__ Bl, int ldb, size_t sB,
              void* __restrict__ Cv, void* __restrict__ Cl2, int ldc, size_t sC, int K,
              const float* __restrict__ bias)
{
    constexpr int NP = NA + NB;
    __shared__ __attribute__((aligned(16))) f16 smem[NP * 4096]; // planes of 128x32 fp16 (8KB)
    f16* sAh = smem;
    f16* sAl = smem + (NA > 1 ? 4096 : 0);
    f16* sBh = smem + NA * 4096;
    f16* sBl = sBh + (NB > 1 ? 4096 : 0);

    int bm, bn;
    if (CAUSAL) {
        int t = blockIdx.x;
        int bi = (int)((sqrtf(8.0f * (float)t + 1.0f) - 1.0f) * 0.5f);
        while ((bi + 1) * (bi + 2) / 2 <= t) ++bi;
        while (bi * (bi + 1) / 2 > t) --bi;
        bm = bi; bn = t - bi * (bi + 1) / 2;
    } else {
        bm = blockIdx.y; bn = blockIdx.x;
    }
    const int m0 = bm * 128, n0 = bn * 128;

    const int tid  = threadIdx.x;
    const int lane = tid & 63;
    const int w    = tid >> 6;

    const f16* Ab  = Ah + sA * blockIdx.z + (size_t)m0 * lda;
    const f16* Alb = (NA > 1) ? (Al + sA * blockIdx.z + (size_t)m0 * lda) : nullptr;
    const f16* Bb  = Bh + sB * blockIdx.z + (size_t)n0 * ldb;
    const f16* Blb = (NB > 1) ? (Bl + sB * blockIdx.z + (size_t)n0 * ldb) : nullptr;

    const int srow = lane >> 2;        // 0..15 within 16-row chunk
    const int scol = (lane & 3) * 8;   // f16 elems within 32-col row (16B granule)

    const int wm = (w >> 1) * 64, wn = (w & 1) * 64;
    const int fr = lane & 15, koff = (lane >> 4) * 8;

    f32x4 acc[4][4] = {};

    for (int k0 = 0; k0 < K; k0 += 32) {
        __syncthreads();  // previous fragment reads complete before overwrite
        #pragma unroll
        for (int j = 0; j < 2; ++j) {
            const int ch = w * 2 + j;            // 16-row chunk 0..7
            const int r  = ch * 16 + srow;
            const int lo = ch * 512;             // f16 elems (1KB chunks)
            gload16(Ab + (size_t)r * lda + k0 + scol, sAh + lo);
            if constexpr (NA > 1) gload16(Alb + (size_t)r * lda + k0 + scol, sAl + lo);
            gload16(Bb + (size_t)r * ldb + k0 + scol, sBh + lo);
            if constexpr (NB > 1) gload16(Blb + (size_t)r * ldb + k0 + scol, sBl + lo);
        }
        __syncthreads();  // compiler drains vmcnt before barrier

        f16x8 a_h[4], a_l[4], b_h[4], b_l[4];
        #pragma unroll
        for (int mi = 0; mi < 4; ++mi) {
            const int r = wm + mi * 16 + fr;
            a_h[mi] = *(const f16x8*)&sAh[r * 32 + koff];
            if constexpr (NA > 1) a_l[mi] = *(const f16x8*)&sAl[r * 32 + koff];
        }
        #pragma unroll
        for (int ni = 0; ni < 4; ++ni) {
            const int r = wn + ni * 16 + fr;
            b_h[ni] = *(const f16x8*)&sBh[r * 32 + koff];
            if constexpr (NB > 1) b_l[ni] = *(const f16x8*)&sBl[r * 32 + koff];
        }
        #pragma unroll
        for (int mi = 0; mi < 4; ++mi) {
            #pragma unroll
            for (int ni = 0; ni < 4; ++ni) {
                acc[mi][ni] = __builtin_amdgcn_mfma_f32_16x16x32_f16(a_h[mi], b_h[ni], acc[mi][ni], 0, 0, 0);
                if constexpr (NA > 1)
                    acc[mi][ni] = __builtin_amdgcn_mfma_f32_16x16x32_f16(a_l[mi], b_h[ni], acc[mi][ni], 0, 0, 0);
                if constexpr (NB > 1)
                    acc[mi][ni] = __builtin_amdgcn_mfma_f32_16x16x32_f16(a_h[mi], b_l[ni], acc[mi][ni], 0, 0, 0);
            }
        }
    }

    // epilogue: C/D layout col=lane&15, row=(lane>>4)*4+reg [m89-verified]
    const int rbase = (lane >> 4) * 4;
    const int ccol  = lane & 15;
    if constexpr (OUTK == 0) {
        float* C = (float*)Cv + sC * blockIdx.z;
        #pragma unroll
        for (int ni = 0; ni < 4; ++ni) {
            const int col = n0 + wn + ni * 16 + ccol;
            const float bv = bias ? bias[col] : 0.0f;
            #pragma unroll
            for (int mi = 0; mi < 4; ++mi)
                #pragma unroll
                for (int r = 0; r < 4; ++r)
                    C[(size_t)(m0 + wm + mi * 16 + rbase + r) * ldc + col] = acc[mi][ni][r] + bv;
        }
    } else if constexpr (OUTK == 1) {
        f16* C = (f16*)Cv + sC * blockIdx.z;
        #pragma unroll
        for (int ni = 0; ni < 4; ++ni) {
            const int col = n0 + wn + ni * 16 + ccol;
            #pragma unroll
            for (int mi = 0; mi < 4; ++mi)
                #pragma unroll
                for (int r = 0; r < 4; ++r)
                    C[(size_t)(m0 + wm + mi * 16 + rbase + r) * ldc + col] = (f16)acc[mi][ni][r];
        }
    } else {
        f16* Ch = (f16*)Cv  + sC * blockIdx.z;
        f16* Cl = (f16*)Cl2 + sC * blockIdx.z;
        #pragma unroll
        for (int ni = 0; ni < 4; ++ni) {
            const int col = n0 + wn + ni * 16 + ccol;
            #pragma unroll
            for (int mi = 0; mi < 4; ++mi)
                #pragma unroll
                for (int r = 0; r < 4; ++r) {
                    const size_t idx = (size_t)(m0 + wm + mi * 16 + rbase + r) * ldc + col;
                    const float x = acc[mi][ni][r];
                    const f16 h = (f16)x;
                    Ch[idx] = h;
                    Cl[idx] = (f16)(x - (float)h);
                }
        }
    }
}

// ---------- softmax over causal-computed scores -> full fp16 P ----------
// scores[b,s,t] valid for t < Vs(s) (tiles bj<=bi). real(t<=s): x/32+1e-13;
// masked(t>s): exactly -1e-13 -> weight c = exp(-1e-13-m)/Z, written analytically.
__global__ __launch_bounds__(256)
void softmax_p(const float* __restrict__ scores, f16* __restrict__ P, int S)
{
    const int s = blockIdx.x;
    const float* srow = scores + ((size_t)blockIdx.y * S + s) * (size_t)S;
    f16* prow = P + ((size_t)blockIdx.y * S + s) * (size_t)S;
    const int tid = threadIdx.x;
    const int c0 = tid * 8;
    const int Vs = ((s >> 7) + 1) << 7;  // computed columns (full diagonal tile)
    const int lane = tid & 63, wv = tid >> 6;

    float v[8];
    const bool have = c0 < Vs;
    float mloc = -3.4e38f;
    if (have) {
        float4 x0 = *(const float4*)(srow + c0);
        float4 x1 = *(const float4*)(srow + c0 + 4);
        const float xs[8] = {x0.x, x0.y, x0.z, x0.w, x1.x, x1.y, x1.z, x1.w};
        #pragma unroll
        for (int j = 0; j < 8; ++j) {
            const int col = c0 + j;
            if (col <= s) { v[j] = fmaf(xs[j], 0.03125f, 1e-13f); mloc = fmaxf(mloc, v[j]); }
            else v[j] = 0.0f;
        }
    }
    #pragma unroll
    for (int off = 1; off < 64; off <<= 1) mloc = fmaxf(mloc, __shfl_xor(mloc, off));
    __shared__ float redm[4], redz[4];
    if (lane == 0) redm[wv] = mloc;
    __syncthreads();
    float m = fmaxf(fmaxf(redm[0], redm[1]), fmaxf(redm[2], redm[3]));
    if (s < S - 1) m = fmaxf(m, -1e-13f);  // masked entries participate in max

    float zloc = 0.0f;
    if (have) {
        #pragma unroll
        for (int j = 0; j < 8; ++j) {
            const int col = c0 + j;
            if (col <= s) { v[j] = expf(v[j] - m); zloc += v[j]; }
        }
    }
    #pragma unroll
    for (int off = 1; off < 64; off <<= 1) zloc += __shfl_xor(zloc, off);
    if (lane == 0) redz[wv] = zloc;
    __syncthreads();
    const float em = expf(-1e-13f - m);
    const float Z = redz[0] + redz[1] + redz[2] + redz[3] + (float)(S - 1 - s) * em;
    const float inv = 1.0f / Z;
    const float cmask = em * inv;

    f16x8 outv;
    #pragma unroll
    for (int j = 0; j < 8; ++j) {
        const int col = c0 + j;
        outv[j] = (f16)((have && col <= s) ? v[j] * inv : cmask);
    }
    *(f16x8*)(prow + c0) = outv;
}

// ================== fallback kernels (f32 in, bf16 split, reg-staged) ==================
__device__ __forceinline__ void split4b(const float4 v, bf16x4& h, bf16x4& l) {
    __bf16 h0 = (__bf16)v.x; float r0 = v.x - (float)h0;
    __bf16 h1 = (__bf16)v.y; float r1 = v.y - (float)h1;
    __bf16 h2 = (__bf16)v.z; float r2 = v.z - (float)h2;
    __bf16 h3 = (__bf16)v.w; float r3 = v.w - (float)h3;
    h[0] = h0; h[1] = h1; h[2] = h2; h[3] = h3;
    l[0] = (__bf16)r0; l[1] = (__bf16)r1; l[2] = (__bf16)r2; l[3] = (__bf16)r3;
}

__global__ __launch_bounds__(256)
void gemm_bt_split(const float* __restrict__ A, int lda, size_t strideA,
                   const float* __restrict__ B, int ldb, size_t strideB,
                   float* __restrict__ C, int ldc, size_t strideC,
                   int K, const float* __restrict__ bias)
{
    constexpr int LDT = 48;
    __shared__ __attribute__((aligned(16))) __bf16 Ah[128 * LDT];
    __shared__ __attribute__((aligned(16))) __bf16 Al[128 * LDT];
    __shared__ __attribute__((aligned(16))) __bf16 Bh[128 * LDT];
    __shared__ __attribute__((aligned(16))) __bf16 Bl[128 * LDT];
    const int tid = threadIdx.x;
    const int m0 = blockIdx.y * 128, n0 = blockIdx.x * 128;
    const float* Ab = A + strideA * blockIdx.z + (size_t)m0 * lda;
    const float* Bb = B + strideB * blockIdx.z + (size_t)n0 * ldb;
    const int lane = tid & 63, wid = tid >> 6;
    const int wm = (wid >> 1) * 64, wn = (wid & 1) * 64;
    const int fr = lane & 15, koff = (lane >> 4) << 3;
    f32x4 acc[4][4] = {};
    for (int k0 = 0; k0 < K; k0 += 32) {
        __syncthreads();
        #pragma unroll
        for (int i = 0; i < 4; ++i) {
            int f4 = tid + 256 * i, row = f4 >> 3, c4 = (f4 & 7) << 2;
            float4 va = *(const float4*)(Ab + (size_t)row * lda + (k0 + c4));
            bf16x4 h, l; split4b(va, h, l);
            *(bf16x4*)&Ah[row * LDT + c4] = h; *(bf16x4*)&Al[row * LDT + c4] = l;
            float4 vb = *(const float4*)(Bb + (size_t)row * ldb + (k0 + c4));
            split4b(vb, h, l);
            *(bf16x4*)&Bh[row * LDT + c4] = h; *(bf16x4*)&Bl[row * LDT + c4] = l;
        }
        __syncthreads();
        bf16x8 ah[4], al[4], bh[4], bl[4];
        #pragma unroll
        for (int mi = 0; mi < 4; ++mi) {
            int r = wm + mi * 16 + fr;
            ah[mi] = *(const bf16x8*)&Ah[r * LDT + koff];
            al[mi] = *(const bf16x8*)&Al[r * LDT + koff];
        }
        #pragma unroll
        for (int ni = 0; ni < 4; ++ni) {
            int r = wn + ni * 16 + fr;
            bh[ni] = *(const bf16x8*)&Bh[r * LDT + koff];
            bl[ni] = *(const bf16x8*)&Bl[r * LDT + koff];
        }
        #pragma unroll
        for (int mi = 0; mi < 4; ++mi)
            #pragma unroll
            for (int ni = 0; ni < 4; ++ni) {
                acc[mi][ni] = __builtin_amdgcn_mfma_f32_16x16x32_bf16(ah[mi], bh[ni], acc[mi][ni], 0, 0, 0);
                acc[mi][ni] = __builtin_amdgcn_mfma_f32_16x16x32_bf16(al[mi], bh[ni], acc[mi][ni], 0, 0, 0);
                acc[mi][ni] = __builtin_amdgcn_mfma_f32_16x16x32_bf16(ah[mi], bl[ni], acc[mi][ni], 0, 0, 0);
            }
    }
    float* Cb = C + strideC * blockIdx.z;
    const int rbase = (lane >> 4) * 4, ccol = lane & 15;
    #pragma unroll
    for (int ni = 0; ni < 4; ++ni) {
        int col = n0 + wn + ni * 16 + ccol;
        float bv = bias ? bias[col] : 0.0f;
        #pragma unroll
        for (int mi = 0; mi < 4; ++mi)
            #pragma unroll
            for (int r = 0; r < 4; ++r)
                Cb[(size_t)(m0 + wm + mi * 16 + rbase + r) * ldc + col] = acc[mi][ni][r] + bv;
    }
}

__global__ __launch_bounds__(256)
void softmax_causal(float* __restrict__ P, int S)
{
    const int row = blockIdx.x;
    float* p = P + ((size_t)blockIdx.y * S + row) * (size_t)S;
    const int tid = threadIdx.x, lane = tid & 63, wid = tid >> 6;
    float v[8];
    float4 x0 = *(const float4*)(p + tid * 4);
    float4 x1 = *(const float4*)(p + 1024 + tid * 4);
    const float xs[8] = {x0.x, x0.y, x0.z, x0.w, x1.x, x1.y, x1.z, x1.w};
    #pragma unroll
    for (int j = 0; j < 8; ++j) {
        int col = (j < 4) ? (tid * 4 + j) : (1024 + tid * 4 + (j - 4));
        v[j] = (col > row) ? -1e-13f : fmaf(xs[j], 0.03125f, 1e-13f);
    }
    float m = v[0];
    #pragma unroll
    for (int j = 1; j < 8; ++j) m = fmaxf(m, v[j]);
    #pragma unroll
    for (int off = 1; off < 64; off <<= 1) m = fmaxf(m, __shfl_xor(m, off));
    __shared__ float red[8];
    if (lane == 0) red[wid] = m;
    __syncthreads();
    m = fmaxf(fmaxf(red[0], red[1]), fmaxf(red[2], red[3]));
    float sm = 0.0f;
    #pragma unroll
    for (int j = 0; j < 8; ++j) { v[j] = expf(v[j] - m); sm += v[j]; }
    #pragma unroll
    for (int off = 1; off < 64; off <<= 1) sm += __shfl_xor(sm, off);
    if (lane == 0) red[4 + wid] = sm;
    __syncthreads();
    sm = red[4] + red[5] + red[6] + red[7];
    const float inv = 1.0f / sm;
    float4 o0, o1;
    o0.x = v[0] * inv; o0.y = v[1] * inv; o0.z = v[2] * inv; o0.w = v[3] * inv;
    o1.x = v[4] * inv; o1.y = v[5] * inv; o1.z = v[6] * inv; o1.w = v[7] * inv;
    *(float4*)(p + tid * 4) = o0;
    *(float4*)(p + 1024 + tid * 4) = o1;
}

// ---------- launch ----------
extern "C" void kernel_launch(void* const* d_in, const int* in_sizes, int n_in,
                              void* d_out, int out_size, void* d_ws, size_t ws_size,
                              hipStream_t stream)
{
    const float* Q  = (const float*)d_in[0];   // [B,S,D]
    const float* Km = (const float*)d_in[1];   // [B,S,D]
    const float* V  = (const float*)d_in[2];   // [B,D,S]
    const float* W  = (const float*)d_in[3];   // [E,D]
    const float* bv = (const float*)d_in[4];   // [E]
    float* out = (float*)d_out;                // [B,S,E]

    constexpr int B = 4, S = 2048, D = 1024, E = 1024;
    const dim3 blk(256);
    const size_t MB = 1u << 20;

    if (ws_size >= 164 * MB) {
        char* w8 = (char*)d_ws;
        float* scores = (float*)w8;                       // 64MB [B,S,S] f32
        f16* attn_h   = (f16*)w8;                         // 16MB, overlays scores (dead after softmax)
        f16* attn_l   = (f16*)(w8 + 16 * MB);             // 16MB, ditto
        f16* Qh = (f16*)(w8 + 64 * MB);                   // 16MB
        f16* Ql = (f16*)(w8 + 80 * MB);                   // 16MB
        f16* P  = (f16*)(w8 + 64 * MB);                   // 32MB, overlays Qh/Ql (dead after QK)
        f16* Kh = (f16*)(w8 + 96 * MB);
        f16* Kl = (f16*)(w8 + 112 * MB);
        f16* Vh = (f16*)(w8 + 128 * MB);
        f16* Vl = (f16*)(w8 + 144 * MB);
        f16* Wh = (f16*)(w8 + 160 * MB);                  // 2MB
        f16* Wl = (f16*)(w8 + 162 * MB);                  // 2MB

        split_f32_to_f16<<<2048, blk, 0, stream>>>(Q,  Qh, Ql, B * S * D / 4);
        split_f32_to_f16<<<2048, blk, 0, stream>>>(Km, Kh, Kl, B * S * D / 4);
        split_f32_to_f16<<<2048, blk, 0, stream>>>(V,  Vh, Vl, B * D * S / 4);
        split_f32_to_f16<<<512,  blk, 0, stream>>>(W,  Wh, Wl, E * D / 4);

        // 1) scores = Q.K^T, lower-triangle tiles only (3-term split)
        constexpr int NT = S / 128;
        gemm_f16<2, 2, 0, true><<<dim3(NT * (NT + 1) / 2, 1, B), blk, 0, stream>>>(
            Qh, Ql, D, (size_t)S * D, Kh, Kl, D, (size_t)S * D,
            scores, nullptr, S, (size_t)S * S, D, nullptr);
        // 2) softmax -> full fp16 P (masked weights analytic)
        softmax_p<<<dim3(S, B), blk, 0, stream>>>(scores, P, S);
        // 3) attn = P.V^T (P pure fp16, V split 2-term), fp16 hi/lo out
        gemm_f16<1, 2, 2, false><<<dim3(D / 128, S / 128, B), blk, 0, stream>>>(
            P, nullptr, S, (size_t)S * S, Vh, Vl, S, (size_t)D * S,
            attn_h, attn_l, D, (size_t)S * D, S, nullptr);
        // 4) out = attn.W^T + b (attn split, W split: 3-term)
        gemm_f16<2, 2, 0, false><<<dim3(E / 128, (B * S) / 128, 1), blk, 0, stream>>>(
            attn_h, attn_l, D, 0, Wh, Wl, D, 0, out, nullptr, E, 0, D, bv);
    } else if (ws_size >= ((size_t)B * S * S + (size_t)B * S * D) * sizeof(float)) {
        float* scores = (float*)d_ws;
        float* attn   = scores + (size_t)B * S * S;
        gemm_bt_split<<<dim3(S / 128, S / 128, B), blk, 0, stream>>>(
            Q, D, (size_t)S * D, Km, D, (size_t)S * D, scores, S, (size_t)S * S, D, nullptr);
        softmax_causal<<<dim3(S, B), blk, 0, stream>>>(scores, S);
        gemm_bt_split<<<dim3(D / 128, S / 128, B), blk, 0, stream>>>(
            scores, S, (size_t)S * S, V, S, (size_t)D * S, attn, D, (size_t)S * D, S, nullptr);
        gemm_bt_split<<<dim3(E / 128, (B * S) / 128, 1), blk, 0, stream>>>(
            attn, D, 0, W, D, 0, out, E, 0, D, bv);
    } else {
        float* sc   = (float*)d_ws;
        float* attn = sc + (size_t)S * S;
        for (int b = 0; b < B; ++b) {
            const float* Qb = Q  + (size_t)b * S * D;
            const float* Kb = Km + (size_t)b * S * D;
            const float* Vb = V  + (size_t)b * D * S;
            float* outb = out + (size_t)b * S * E;
            gemm_bt_split<<<dim3(S / 128, S / 128, 1), blk, 0, stream>>>(
                Qb, D, 0, Kb, D, 0, sc, S, 0, D, nullptr);
            softmax_causal<<<dim3(S, 1), blk, 0, stream>>>(sc, S);
            gemm_bt_split<<<dim3(D / 128, S / 128, 1), blk, 0, stream>>>(
                sc, S, 0, Vb, S, 0, attn, D, 0, S, nullptr);
            gemm_bt_split<<<dim3(E / 128, S / 128, 1), blk, 0, stream>>>(
                attn, D, 0, W, D, 0, outb, E, 0, D, bv);
        }
    }
}